// Round 9
// baseline (830.336 us; speedup 1.0000x reference)
//
#include <hip/hip_runtime.h>
#include <math.h>
#include <float.h>

// GNN layer, fp32, lean-CSR (atomic-free segment reductions).
// Algebraic fusion: hn = agg@Wh is NEVER materialized; the output GEMM is pushed
// BEFORE the gather and fused INTO the segment-max kernel:
//   u[n]  = agg[n]·fu,  fu = Wh@fw[:64]   (k_fuse precomputes fu,fv)
//   v[n]  = agg[n]·fv,  fv = Wh@fw[64:]
//   agg2  = agg@W2,     W2 = Wh@Wnode_w   (epilogue of k_agg2; agg never hits HBM)
//   out   = (sum_e w·agg2[obj_e] + (sum_e w)·Wnode_b)/gsum   (k_aggsum epilogue)
// Gather kernels use 4-EDGE SOFTWARE PIPELINING: the per-edge chain
// shfl->addr->gather->combine is the latency limiter (r6/r7/r8: three different
// phase-2 variants all 225us => phase-1 bound); 4 independent row gathers in
// flight per iteration restore ILP. FP order preserved (sequential combine).
// K0 k_tables : s2[rel]=rela@Wr, s3[b]=rela[q_rel[b]]@Wqr_w+b          (tiny)
// K0b k_fuse  : W2 = Wh@Wnode_w; fu,fv = Wh@attn_fc_w halves           (tiny)
// K1 k_proj   : P = hidden@Ws (N x 5)
// K2 k_hist   : cnt[obj]++, cnt[N+sub]++
// K3 scan     : exclusive scan of cnt (2N, concatenated) -> off; off[N]==E
// K4 k_scatter: per edge: alpha from P/s2/s3; rec_obj[p]={sub,rel,alpha},
//               rec_sub[q]={obj,sub}  (cursor atomics on copy of off)
// K5 k_agg2   : W2 -> LDS once/block; wave/8-nodes (by obj-CSR): phase1 max over
//               edges of alpha*(hs-hr), 4-edge pipelined -> row in LDS + u,v
//               shfl-reduce; phase2 row@W2 loop-interchanged (k4 outer) -> agg2
// K7 k_scores : stream rec_sub: s=leaky(u[sub]+v[obj]+b) -> scores[pos]; softmax partials
// K8 k_softmax_final : gmax, gsum
// K9 k_aggsum : wave/8-nodes (by sub-CSR), 4-edge pipelined, exp folded at record
//               load (once per edge): out = (sum w*agg2[obj] + wa*b)/gsum -> d_out

#define SCAN_BLK 256
#define SCAN_ITEMS 4
#define SCAN_CHUNK (SCAN_BLK * SCAN_ITEMS)
#define SOFT_G 2048
#define NPW 8        // nodes per wave in batched CSR kernels

// ---------- K0
__global__ void k_tables(const float* __restrict__ rela, const float* __restrict__ Wr,
                         const float* __restrict__ Wqr_w, const float* __restrict__ Wqr_b,
                         const int* __restrict__ q_rel,
                         float* __restrict__ s2, float* __restrict__ s3,
                         int nrel, int batch) {
  int tid = blockIdx.x * blockDim.x + threadIdx.x;
  int stride = gridDim.x * blockDim.x;
  for (int idx = tid; idx < nrel * 5; idx += stride) {
    int r = idx / 5, j = idx % 5;
    float acc = 0.f;
    for (int k = 0; k < 64; k++) acc += rela[r * 64 + k] * Wr[k * 5 + j];
    s2[idx] = acc;
  }
  for (int idx = tid; idx < batch * 5; idx += stride) {
    int b = idx / 5, j = idx % 5;
    int qr = q_rel[b];
    float acc = Wqr_b[j];
    for (int k = 0; k < 64; k++) acc += rela[qr * 64 + k] * Wqr_w[k * 5 + j];
    s3[idx] = acc;
  }
}

// ---------- K0b: W2 = Wh @ Wnode_w (64x64); fu,fv = Wh @ attn_fc_w halves
__global__ void k_fuse(const float* __restrict__ Wh, const float* __restrict__ Wn,
                       const float* __restrict__ fw,
                       float* __restrict__ W2, float* __restrict__ fuv) {
  int tid = threadIdx.x;
  for (int idx = tid; idx < 64 * 64; idx += 256) {
    int k = idx >> 6, m = idx & 63;
    float acc = 0.f;
    for (int j = 0; j < 64; j++) acc += Wh[k * 64 + j] * Wn[j * 64 + m];
    W2[idx] = acc;
  }
  if (tid < 128) {
    int k = tid & 63, h = tid >> 6;  // h=0: fu, h=1: fv
    float acc = 0.f;
    for (int j = 0; j < 64; j++) acc += Wh[k * 64 + j] * fw[h * 64 + j];
    fuv[h * 64 + k] = acc;
  }
}

// ---------- K1: P = hidden @ Ws
__global__ void __launch_bounds__(256, 2)
k_proj(const float* __restrict__ hidden, const float* __restrict__ Ws_g,
       float* __restrict__ P, int N) {
  int n = blockIdx.x * blockDim.x + threadIdx.x;
  if (n >= N) return;
  float hs[64];
  const float4* h4 = (const float4*)(hidden + (size_t)n * 64);
#pragma unroll
  for (int k4 = 0; k4 < 16; k4++) {
    float4 h = h4[k4];
    hs[k4 * 4 + 0] = h.x; hs[k4 * 4 + 1] = h.y; hs[k4 * 4 + 2] = h.z; hs[k4 * 4 + 3] = h.w;
  }
  float acc[5] = {0.f, 0.f, 0.f, 0.f, 0.f};
#pragma unroll
  for (int k = 0; k < 64; k++) {
    float h = hs[k];
#pragma unroll
    for (int j = 0; j < 5; j++) acc[j] += h * Ws_g[k * 5 + j];  // uniform idx -> s_load
  }
#pragma unroll
  for (int j = 0; j < 5; j++) P[(size_t)n * 5 + j] = acc[j];
}

// ---------- K2
__global__ void k_hist(const int* __restrict__ edges, int* __restrict__ cnt, int E, int N) {
  int e = blockIdx.x * blockDim.x + threadIdx.x;
  if (e < E) {
    int sub = edges[e * 6 + 4];
    int obj = edges[e * 6 + 5];
    atomicAdd(&cnt[obj], 1);
    atomicAdd(&cnt[N + sub], 1);
  }
}

// ---------- K3a
__global__ void k_scan_partial(const int* __restrict__ cnt, int* __restrict__ part, int n) {
  __shared__ int sdata[SCAN_BLK];
  int base = blockIdx.x * SCAN_CHUNK + threadIdx.x * SCAN_ITEMS;
  int s = 0;
#pragma unroll
  for (int j = 0; j < SCAN_ITEMS; j++) { int i = base + j; if (i < n) s += cnt[i]; }
  sdata[threadIdx.x] = s;
  __syncthreads();
  for (int d = SCAN_BLK / 2; d > 0; d >>= 1) {
    if (threadIdx.x < d) sdata[threadIdx.x] += sdata[threadIdx.x + d];
    __syncthreads();
  }
  if (threadIdx.x == 0) part[blockIdx.x] = sdata[0];
}

// ---------- K3b (nblk <= 1024)
__global__ void k_scan_top(int* part, int nblk) {
  __shared__ int lds[1024];
  int tid = threadIdx.x;
  int v = (tid < nblk) ? part[tid] : 0;
  lds[tid] = v;
  __syncthreads();
  for (int d = 1; d < 1024; d <<= 1) {
    int t = (tid >= d) ? lds[tid - d] : 0;
    __syncthreads();
    lds[tid] += t;
    __syncthreads();
  }
  if (tid < nblk) part[tid] = lds[tid] - v;  // exclusive
}

// ---------- K3c
__global__ void k_scan_final(const int* __restrict__ cnt, const int* __restrict__ part,
                             int* __restrict__ off, int n) {
  __shared__ int lds[SCAN_BLK];
  int tid = threadIdx.x;
  int base = blockIdx.x * SCAN_CHUNK + tid * SCAN_ITEMS;
  int c[SCAN_ITEMS];
  int s = 0;
#pragma unroll
  for (int j = 0; j < SCAN_ITEMS; j++) { int i = base + j; c[j] = (i < n) ? cnt[i] : 0; s += c[j]; }
  int v = s;
  lds[tid] = s;
  __syncthreads();
  for (int d = 1; d < SCAN_BLK; d <<= 1) {
    int t = (tid >= d) ? lds[tid - d] : 0;
    __syncthreads();
    lds[tid] += t;
    __syncthreads();
  }
  int run = part[blockIdx.x] + (lds[tid] - v);
#pragma unroll
  for (int j = 0; j < SCAN_ITEMS; j++) { int i = base + j; if (i < n) off[i] = run; run += c[j]; }
}

// ---------- K4: alpha + scatter packed records
__global__ void k_scatter(const int* __restrict__ edges, const float* __restrict__ P,
                          const float* __restrict__ s2, const float* __restrict__ s3,
                          const float* __restrict__ walpha_w, const float* __restrict__ walpha_b,
                          int* __restrict__ cur, int4* __restrict__ rec_obj,
                          int2* __restrict__ rec_sub, int E, int N) {
  int e = blockIdx.x * blockDim.x + threadIdx.x;
  if (e >= E) return;
  int ridx = edges[e * 6 + 0];
  int rel  = edges[e * 6 + 2];
  int sub  = edges[e * 6 + 4];
  int obj  = edges[e * 6 + 5];
  float z = walpha_b[0];
#pragma unroll
  for (int j = 0; j < 5; j++) {
    float vj = P[(size_t)sub * 5 + j] + s2[rel * 5 + j] + s3[ridx * 5 + j];
    z += fmaxf(vj, 0.f) * walpha_w[j];
  }
  float a = 1.f / (1.f + expf(-z));
  int p = atomicAdd(&cur[obj], 1);
  rec_obj[p] = make_int4(sub, rel, __float_as_int(a), 0);
  int q = atomicAdd(&cur[N + sub], 1) - E;
  rec_sub[q] = make_int2(obj, sub);
}

// ---------- K5: fused segment_max by obj + (row@W2) + u,v  (atomic-free, wave/NPW-nodes)
// Phase 1: 4-edge pipelined gather/max (4 independent row gathers in flight);
//          clamped window indices for tail chunks (duplicate loads, cache-hot);
//          combine guarded + sequential => FP order identical to serial loop.
// Phase 2: k4 outer, nodes inner; W2 in LDS (16 KB); acc[NPW] regs.
__global__ void __launch_bounds__(256, 4)
k_agg2(const int* __restrict__ off, const int4* __restrict__ rec_obj,
       const float* __restrict__ hidden, const float* __restrict__ rela,
       const float* __restrict__ W2, const float* __restrict__ fuv,
       float* __restrict__ agg2, float* __restrict__ u, float* __restrict__ v,
       int N) {
  __shared__ float w2s[64 * 64];       // 16 KB
  __shared__ float rows[4][NPW][64];   // 8 KB
  // cooperative W2 stage (before any early-exit: all threads hit the barrier)
  for (int idx = threadIdx.x; idx < 1024; idx += 256)
    ((float4*)w2s)[idx] = ((const float4*)W2)[idx];
  __syncthreads();
  int lane  = threadIdx.x & 63;
  int wslot = threadIdx.x >> 6;
  int wid   = blockIdx.x * (blockDim.x >> 6) + wslot;
  int node0 = wid * NPW;
  if (node0 >= N) return;
  float fu = fuv[lane], fv = fuv[64 + lane];
  // CSR boundaries off[min(node0+l, N)], l=0..NPW (off[N]==E)
  int ov = 0;
  if (lane <= NPW) {
    int idx = node0 + lane;
    if (idx > N) idx = N;
    ov = off[idx];
  }
  int B   = __shfl(ov, 0);
  int End = __shfl(ov, NPW);
  int lbase = B;
  int rx = 0, ry = 0; float rz = 0.f;
  {
    int p = lbase + lane;
    if (p < End) { int4 r = rec_obj[p]; rx = r.x; ry = r.y; rz = __int_as_float(r.z); }
  }
  int cur = B;
  // ---- phase 1: 4-edge pipelined gather/max per node; row -> LDS; u,v reduce
  for (int i = 0; i < NPW; i++) {
    int node = node0 + i;
    if (node >= N) break;
    int en = __shfl(ov, i + 1);
    int bst = cur;
    float vmax = -FLT_MAX;
    while (cur < en) {
      int idx = cur - lbase;
      if (idx >= 64) {           // wave-uniform reload of next 64 records
        lbase += 64;
        int p = lbase + lane;
        if (p < End) { int4 r = rec_obj[p]; rx = r.x; ry = r.y; rz = __int_as_float(r.z); }
        idx = 0;
      }
      int c = min(min(en - cur, 64 - idx), 4);   // wave-uniform chunk
      int i1 = idx + ((c > 1) ? 1 : 0);
      int i2 = idx + ((c > 2) ? 2 : 0);
      int i3 = idx + ((c > 3) ? 3 : 0);
      int s0 = __shfl(rx, idx); int g0 = __shfl(ry, idx); float a0 = __shfl(rz, idx);
      int s1 = __shfl(rx, i1);  int g1 = __shfl(ry, i1);  float a1 = __shfl(rz, i1);
      int s2 = __shfl(rx, i2);  int g2 = __shfl(ry, i2);  float a2 = __shfl(rz, i2);
      int s3 = __shfl(rx, i3);  int g3 = __shfl(ry, i3);  float a3 = __shfl(rz, i3);
      float h0 = hidden[(size_t)s0 * 64 + lane];   // 4 independent gathers in flight
      float h1 = hidden[(size_t)s1 * 64 + lane];
      float h2 = hidden[(size_t)s2 * 64 + lane];
      float h3 = hidden[(size_t)s3 * 64 + lane];
      float e0 = rela[g0 * 64 + lane];
      float e1 = rela[g1 * 64 + lane];
      float e2 = rela[g2 * 64 + lane];
      float e3 = rela[g3 * 64 + lane];
      vmax = fmaxf(vmax, a0 * (h0 - e0));          // same order as serial loop
      if (c > 1) vmax = fmaxf(vmax, a1 * (h1 - e1));
      if (c > 2) vmax = fmaxf(vmax, a2 * (h2 - e2));
      if (c > 3) vmax = fmaxf(vmax, a3 * (h3 - e3));
      cur += c;
    }
    float rowv = (en > bst) ? vmax : 0.f;
    rows[wslot][i][lane] = rowv;
    float ur = rowv * fu, vr = rowv * fv;
#pragma unroll
    for (int m = 32; m > 0; m >>= 1) {
      ur += __shfl_xor(ur, m);
      vr += __shfl_xor(vr, m);
    }
    if (lane == 0) { u[node] = ur; v[node] = vr; }
  }
  // ---- phase 2: k4 outer, nodes inner (4 weights live; no remat possible)
  int nv = min(NPW, N - node0);
  float acc[NPW];
#pragma unroll
  for (int i = 0; i < NPW; i++) acc[i] = 0.f;
  for (int k4 = 0; k4 < 16; k4++) {
    float w0 = w2s[(k4 * 4 + 0) * 64 + lane];  // lane-contig: 2 lanes/bank, free
    float w1 = w2s[(k4 * 4 + 1) * 64 + lane];
    float w2 = w2s[(k4 * 4 + 2) * 64 + lane];
    float w3 = w2s[(k4 * 4 + 3) * 64 + lane];
#pragma unroll
    for (int i = 0; i < NPW; i++) {
      float4 r4 = *(const float4*)&rows[wslot][i][k4 * 4];   // uniform -> broadcast
      acc[i] = fmaf(r4.x, w0, fmaf(r4.y, w1, fmaf(r4.z, w2, fmaf(r4.w, w3, acc[i]))));
    }
  }
  for (int i = 0; i < nv; i++)
    agg2[(size_t)(node0 + i) * 64 + lane] = acc[i];   // coalesced
}

// ---------- K7: scores in sub-CSR position order + softmax partials
__global__ void k_scores(const int2* __restrict__ rec_sub, const float* __restrict__ u,
                         const float* __restrict__ v, const float* __restrict__ fb,
                         float* __restrict__ scores, float* __restrict__ pmax,
                         float* __restrict__ psum, int E) {
  __shared__ float red_m[256], red_s[256];
  float b = fb[0];
  float lm = -FLT_MAX, ls = 0.f;
  for (int pos = blockIdx.x * blockDim.x + threadIdx.x; pos < E; pos += gridDim.x * blockDim.x) {
    int2 r = rec_sub[pos];
    float s = u[r.y] + v[r.x] + b;
    s = (s >= 0.f) ? s : 0.2f * s;
    scores[pos] = s;
    if (s > lm) { ls = ls * expf(lm - s) + 1.f; lm = s; }
    else        { ls += expf(s - lm); }
  }
  red_m[threadIdx.x] = lm; red_s[threadIdx.x] = ls;
  __syncthreads();
  for (int d = blockDim.x / 2; d > 0; d >>= 1) {
    if (threadIdx.x < d) {
      float m1 = red_m[threadIdx.x], s1 = red_s[threadIdx.x];
      float m2 = red_m[threadIdx.x + d], s2 = red_s[threadIdx.x + d];
      float m = fmaxf(m1, m2);
      float s = 0.f;
      if (m > -FLT_MAX) s = s1 * expf(m1 - m) + s2 * expf(m2 - m);
      red_m[threadIdx.x] = m; red_s[threadIdx.x] = s;
    }
    __syncthreads();
  }
  if (threadIdx.x == 0) { pmax[blockIdx.x] = red_m[0]; psum[blockIdx.x] = red_s[0]; }
}

// ---------- K8
__global__ void k_softmax_final(const float* __restrict__ pmax, const float* __restrict__ psum,
                                float* __restrict__ scal, int G) {
  __shared__ float red_m[256], red_s[256];
  float lm = -FLT_MAX, ls = 0.f;
  for (int i = threadIdx.x; i < G; i += 256) {
    float m2 = pmax[i], s2 = psum[i];
    if (m2 > lm) { ls = ls * expf(lm - m2) + s2; lm = m2; }
    else         { ls += s2 * expf(m2 - lm); }
  }
  red_m[threadIdx.x] = lm; red_s[threadIdx.x] = ls;
  __syncthreads();
  for (int d = 128; d > 0; d >>= 1) {
    if (threadIdx.x < d) {
      float m1 = red_m[threadIdx.x], s1 = red_s[threadIdx.x];
      float m2 = red_m[threadIdx.x + d], s2 = red_s[threadIdx.x + d];
      float m = fmaxf(m1, m2);
      float s = 0.f;
      if (m > -FLT_MAX) s = s1 * expf(m1 - m) + s2 * expf(m2 - m);
      red_m[threadIdx.x] = m; red_s[threadIdx.x] = s;
    }
    __syncthreads();
  }
  if (threadIdx.x == 0) { scal[0] = red_m[0]; scal[1] = red_s[0]; }
}

// ---------- K9: weighted segment_sum by sub (atomic-free, wave/NPW-nodes)
// 4-edge pipelined; exp(score-gmax) folded at record load (once per edge —
// replaces the k_expw pass, identical values). Fused epilogue writes FINAL
// out = (acc + wa*bias)/gsum.
__global__ void k_aggsum(const int* __restrict__ off, const int2* __restrict__ rec_sub,
                         const float* __restrict__ scores, const float* __restrict__ agg2,
                         const float* __restrict__ bias, const float* __restrict__ scal,
                         float* __restrict__ out, int N, int E) {
  int lane = threadIdx.x & 63;
  int wid  = blockIdx.x * (blockDim.x >> 6) + (threadIdx.x >> 6);
  int node0 = wid * NPW;
  if (node0 >= N) return;
  float bl = bias[lane];
  float gmax = scal[0];
  float inv = 1.f / scal[1];
  int ov = 0;
  if (lane <= NPW) {
    int idx = node0 + lane;
    ov = (idx >= N) ? E : (off[N + idx] - E);
  }
  int B   = __shfl(ov, 0);
  int End = __shfl(ov, NPW);
  int lbase = B;
  int objr = 0; float wr = 0.f;
  {
    int p = lbase + lane;
    if (p < End) { objr = rec_sub[p].x; wr = expf(scores[p] - gmax); }
  }
  int cur = B;
  for (int i = 0; i < NPW; i++) {
    int node = node0 + i;
    if (node >= N) break;
    int en = __shfl(ov, i + 1);
    float acc = 0.f, wa = 0.f;
    while (cur < en) {
      int idx = cur - lbase;
      if (idx >= 64) {           // wave-uniform reload
        lbase += 64;
        int p = lbase + lane;
        if (p < End) { objr = rec_sub[p].x; wr = expf(scores[p] - gmax); }
        idx = 0;
      }
      int c = min(min(en - cur, 64 - idx), 4);   // wave-uniform chunk
      int i1 = idx + ((c > 1) ? 1 : 0);
      int i2 = idx + ((c > 2) ? 2 : 0);
      int i3 = idx + ((c > 3) ? 3 : 0);
      int o0 = __shfl(objr, idx); float w0 = __shfl(wr, idx);
      int o1 = __shfl(objr, i1);  float w1 = __shfl(wr, i1);
      int o2 = __shfl(objr, i2);  float w2 = __shfl(wr, i2);
      int o3 = __shfl(objr, i3);  float w3 = __shfl(wr, i3);
      float h0 = agg2[(size_t)o0 * 64 + lane];   // 4 independent gathers in flight
      float h1 = agg2[(size_t)o1 * 64 + lane];
      float h2 = agg2[(size_t)o2 * 64 + lane];
      float h3 = agg2[(size_t)o3 * 64 + lane];
      acc += w0 * h0; wa += w0;                  // same order as serial loop
      if (c > 1) { acc += w1 * h1; wa += w1; }
      if (c > 2) { acc += w2 * h2; wa += w2; }
      if (c > 3) { acc += w3 * h3; wa += w3; }
      cur += c;
    }
    out[(size_t)node * 64 + lane] = (acc + wa * bl) * inv;
  }
}

extern "C" void kernel_launch(void* const* d_in, const int* in_sizes, int n_in,
                              void* d_out, int out_size, void* d_ws, size_t ws_size,
                              hipStream_t stream) {
  const float* hidden    = (const float*)d_in[0];
  const float* rela      = (const float*)d_in[1];
  const float* Ws        = (const float*)d_in[2];
  const float* Wr        = (const float*)d_in[3];
  const float* Wqr_w     = (const float*)d_in[4];
  const float* Wqr_b     = (const float*)d_in[5];
  const float* walpha_w  = (const float*)d_in[6];
  const float* walpha_b  = (const float*)d_in[7];
  const float* Wh        = (const float*)d_in[8];
  const float* attn_fc_w = (const float*)d_in[9];
  const float* attn_fc_b = (const float*)d_in[10];
  const float* Wnode_w   = (const float*)d_in[11];
  const float* Wnode_b   = (const float*)d_in[12];
  const int*   q_rel     = (const int*)d_in[14];
  const int*   edges     = (const int*)d_in[15];

  int N = in_sizes[0] / 64;      // 500000
  int E = in_sizes[15] / 6;      // 1000000
  int nrel = in_sizes[1] / 64;   // 401
  int batch = in_sizes[14];      // 32

  // workspace layout: every buffer 256 B aligned
  char* w = (char*)d_ws;
  size_t o = 0;
  #define WS_ALLOC(ptr_t, name, bytes) \
    ptr_t name = (ptr_t)(w + o); o = (o + (size_t)(bytes) + 255) & ~(size_t)255;
  WS_ALLOC(float*, agg2,    (size_t)N * 64 * 4)    // agg@W2 (agg itself never stored)
  WS_ALLOC(float*, P,       (size_t)N * 5 * 4)     // later: u,v alias here
  WS_ALLOC(int4*,  rec_obj, (size_t)E * 16)
  WS_ALLOC(int2*,  rec_sub, (size_t)E * 8)
  WS_ALLOC(int*,   cnt,     (size_t)2 * N * 4)     // counts -> cursors; later scores alias
  WS_ALLOC(int*,   off,     (size_t)2 * N * 4)
  WS_ALLOC(int*,   part,    1024 * 4)
  WS_ALLOC(float*, pmax,    SOFT_G * 4)
  WS_ALLOC(float*, psum,    SOFT_G * 4)
  WS_ALLOC(float*, s2t,     (size_t)nrel * 5 * 4)
  WS_ALLOC(float*, s3t,     (size_t)batch * 5 * 4)
  WS_ALLOC(float*, scal,    2 * 4)
  WS_ALLOC(float*, W2,      64 * 64 * 4)
  WS_ALLOC(float*, fuv,     2 * 64 * 4)
  #undef WS_ALLOC

  float* u = P;                 // P dead after k_scatter
  float* v = P + N;
  float* scores = (float*)cnt;  // cursors dead after k_scatter (E*4 <= 2N*4)

  k_tables<<<16, 256, 0, stream>>>(rela, Wr, Wqr_w, Wqr_b, q_rel, s2t, s3t, nrel, batch);
  k_fuse<<<1, 256, 0, stream>>>(Wh, Wnode_w, attn_fc_w, W2, fuv);
  k_proj<<<(N + 255) / 256, 256, 0, stream>>>(hidden, Ws, P, N);
  hipMemsetAsync(cnt, 0, (size_t)2 * N * 4, stream);
  k_hist<<<(E + 255) / 256, 256, 0, stream>>>(edges, cnt, E, N);
  int SCAN_N = 2 * N;
  int nblk = (SCAN_N + SCAN_CHUNK - 1) / SCAN_CHUNK;  // 977 <= 1024
  k_scan_partial<<<nblk, SCAN_BLK, 0, stream>>>(cnt, part, SCAN_N);
  k_scan_top<<<1, 1024, 0, stream>>>(part, nblk);
  k_scan_final<<<nblk, SCAN_BLK, 0, stream>>>(cnt, part, off, SCAN_N);
  hipMemcpyAsync(cnt, off, (size_t)2 * N * 4, hipMemcpyDeviceToDevice, stream);  // cursors
  k_scatter<<<(E + 255) / 256, 256, 0, stream>>>(edges, P, s2t, s3t, walpha_w, walpha_b,
                                                 cnt, rec_obj, rec_sub, E, N);
  // batched CSR kernels: NPW nodes per wave, 4 waves per block
  int csr_blocks = (N + NPW * 4 - 1) / (NPW * 4);
  k_agg2<<<csr_blocks, 256, 0, stream>>>(off, rec_obj, hidden, rela, W2, fuv,
                                         agg2, u, v, N);
  k_scores<<<SOFT_G, 256, 0, stream>>>(rec_sub, u, v, attn_fc_b, scores, pmax, psum, E);
  k_softmax_final<<<1, 256, 0, stream>>>(pmax, psum, scal, SOFT_G);
  k_aggsum<<<csr_blocks, 256, 0, stream>>>(off, rec_sub, scores, agg2,
                                           Wnode_b, scal, (float*)d_out, N, E);
}

// Round 10
// 730.432 us; speedup vs baseline: 1.1368x; 1.1368x over previous
//
#include <hip/hip_runtime.h>
#include <math.h>
#include <float.h>

// GNN layer, fp32, lean-CSR (atomic-free segment reductions). SPLIT structure
// (r5 champion) — fused k_agg2 (r6-r9) was issue-bound at 225-240us, worse than
// the split's gather (~95) + thread-per-node GEMM (104).
// Algebraic fusion retained: hn = agg@Wh never materialized.
//   u[n] = agg[n]·fu, v[n] = agg[n]·fv   (fu,fv = Wh@attn_fc_w halves)
//   agg2 = agg@W2, W2 = Wh@Wnode_w
//   out  = (sum_e w·agg2[obj_e] + (sum_e w)·Wnode_b)/gsum
// Buffer routing (in-place races avoided): k_agg: gather->max -> d_out (agg);
// k_trans2: d_out -> ws.agg2 (+u,v); k_aggsum: gather ws.agg2 -> d_out (final).
// K0 k_prep     : zero cnt + s2/s3 tables + W2 + fuv                  (1 dispatch)
// K1 k_proj_hist: P = hidden@Ws  AND  cnt[obj]++/cnt[N+sub]++         (merged)
// K3 scan       : 3-dispatch exclusive scan; scan_final also writes cursor copy
// K4 k_scatter  : per edge: alpha; rec_obj={sub,rel,alpha}, rec_sub={obj,sub}
// K5 k_agg      : wave/8-nodes (obj-CSR): max alpha*(hs-hr) -> d_out
// K6 k_trans2   : h-split thread-per-node GEMM: acc[32]/thread, s_load weights,
//                 u/v dots, LDS-staged coalesced half-row writes -> ws.agg2
// K7 k_scores   : s=leaky(u[sub]+v[obj]+b) -> scores; softmax partials
// K8 k_softmax_final : gmax, gsum
// K9 k_aggsum   : wave/8-nodes (sub-CSR), exp folded at record load:
//                 out = (sum w*agg2[obj] + wa*b)/gsum -> d_out

#define SCAN_BLK 256
#define SCAN_ITEMS 4
#define SCAN_CHUNK (SCAN_BLK * SCAN_ITEMS)
#define SOFT_G 2048
#define NPW 8        // nodes per wave in batched CSR kernels

// ---------- K0: prep (zero cnt, s2/s3, W2=Wh@Wnode_w, fuv=Wh@attn_fc_w halves)
__global__ void k_prep(const float* __restrict__ rela, const float* __restrict__ Wr,
                       const float* __restrict__ Wqr_w, const float* __restrict__ Wqr_b,
                       const int* __restrict__ q_rel, const float* __restrict__ Wh,
                       const float* __restrict__ Wn, const float* __restrict__ fw,
                       float* __restrict__ s2, float* __restrict__ s3,
                       float* __restrict__ W2, float* __restrict__ fuv,
                       int* __restrict__ cnt,
                       int nrel, int batch, int n2) {
  int tid = blockIdx.x * blockDim.x + threadIdx.x;
  int stride = gridDim.x * blockDim.x;
  for (int i = tid; i < n2; i += stride) cnt[i] = 0;
  for (int idx = tid; idx < nrel * 5; idx += stride) {
    int r = idx / 5, j = idx % 5;
    float acc = 0.f;
    for (int k = 0; k < 64; k++) acc += rela[r * 64 + k] * Wr[k * 5 + j];
    s2[idx] = acc;
  }
  for (int idx = tid; idx < batch * 5; idx += stride) {
    int b = idx / 5, j = idx % 5;
    int qr = q_rel[b];
    float acc = Wqr_b[j];
    for (int k = 0; k < 64; k++) acc += rela[qr * 64 + k] * Wqr_w[k * 5 + j];
    s3[idx] = acc;
  }
  for (int idx = tid; idx < 64 * 64; idx += stride) {
    int k = idx >> 6, m = idx & 63;
    float acc = 0.f;
    for (int j = 0; j < 64; j++) acc += Wh[k * 64 + j] * Wn[j * 64 + m];
    W2[idx] = acc;
  }
  for (int idx = tid; idx < 128; idx += stride) {
    int k = idx & 63, h = idx >> 6;  // h=0: fu, h=1: fv
    float acc = 0.f;
    for (int j = 0; j < 64; j++) acc += Wh[k * 64 + j] * fw[h * 64 + j];
    fuv[h * 64 + k] = acc;
  }
}

// ---------- K1: P = hidden @ Ws  (+ edge histogram, merged)
__global__ void k_proj_hist(const float* __restrict__ hidden, const float* __restrict__ Ws_g,
                            const int* __restrict__ edges, float* __restrict__ P,
                            int* __restrict__ cnt, int N, int E) {
  int g = blockIdx.x * blockDim.x + threadIdx.x;
  if (g < E) {
    int sub = edges[g * 6 + 4];
    int obj = edges[g * 6 + 5];
    atomicAdd(&cnt[obj], 1);
    atomicAdd(&cnt[N + sub], 1);
  }
  if (g < N) {
    float hs[64];
    const float4* h4 = (const float4*)(hidden + (size_t)g * 64);
#pragma unroll
    for (int k4 = 0; k4 < 16; k4++) {
      float4 h = h4[k4];
      hs[k4 * 4 + 0] = h.x; hs[k4 * 4 + 1] = h.y; hs[k4 * 4 + 2] = h.z; hs[k4 * 4 + 3] = h.w;
    }
    float acc[5] = {0.f, 0.f, 0.f, 0.f, 0.f};
#pragma unroll
    for (int k = 0; k < 64; k++) {
      float h = hs[k];
#pragma unroll
      for (int j = 0; j < 5; j++) acc[j] += h * Ws_g[k * 5 + j];  // uniform -> s_load
    }
#pragma unroll
    for (int j = 0; j < 5; j++) P[(size_t)g * 5 + j] = acc[j];
  }
}

// ---------- K3a
__global__ void k_scan_partial(const int* __restrict__ cnt, int* __restrict__ part, int n) {
  __shared__ int sdata[SCAN_BLK];
  int base = blockIdx.x * SCAN_CHUNK + threadIdx.x * SCAN_ITEMS;
  int s = 0;
#pragma unroll
  for (int j = 0; j < SCAN_ITEMS; j++) { int i = base + j; if (i < n) s += cnt[i]; }
  sdata[threadIdx.x] = s;
  __syncthreads();
  for (int d = SCAN_BLK / 2; d > 0; d >>= 1) {
    if (threadIdx.x < d) sdata[threadIdx.x] += sdata[threadIdx.x + d];
    __syncthreads();
  }
  if (threadIdx.x == 0) part[blockIdx.x] = sdata[0];
}

// ---------- K3b (nblk <= 1024)
__global__ void k_scan_top(int* part, int nblk) {
  __shared__ int lds[1024];
  int tid = threadIdx.x;
  int v = (tid < nblk) ? part[tid] : 0;
  lds[tid] = v;
  __syncthreads();
  for (int d = 1; d < 1024; d <<= 1) {
    int t = (tid >= d) ? lds[tid - d] : 0;
    __syncthreads();
    lds[tid] += t;
    __syncthreads();
  }
  if (tid < nblk) part[tid] = lds[tid] - v;  // exclusive
}

// ---------- K3c: writes off AND the cursor copy (into cnt, read-then-overwrite
// by the same thread -> safe; replaces the D2D memcpy dispatch)
__global__ void k_scan_final(int* __restrict__ cnt, const int* __restrict__ part,
                             int* __restrict__ off, int n) {
  __shared__ int lds[SCAN_BLK];
  int tid = threadIdx.x;
  int base = blockIdx.x * SCAN_CHUNK + tid * SCAN_ITEMS;
  int c[SCAN_ITEMS];
  int s = 0;
#pragma unroll
  for (int j = 0; j < SCAN_ITEMS; j++) { int i = base + j; c[j] = (i < n) ? cnt[i] : 0; s += c[j]; }
  int v = s;
  lds[tid] = s;
  __syncthreads();
  for (int d = 1; d < SCAN_BLK; d <<= 1) {
    int t = (tid >= d) ? lds[tid - d] : 0;
    __syncthreads();
    lds[tid] += t;
    __syncthreads();
  }
  int run = part[blockIdx.x] + (lds[tid] - v);
#pragma unroll
  for (int j = 0; j < SCAN_ITEMS; j++) {
    int i = base + j;
    if (i < n) { off[i] = run; cnt[i] = run; }  // cnt becomes the cursor array
    run += c[j];
  }
}

// ---------- K4: alpha + scatter packed records
__global__ void k_scatter(const int* __restrict__ edges, const float* __restrict__ P,
                          const float* __restrict__ s2, const float* __restrict__ s3,
                          const float* __restrict__ walpha_w, const float* __restrict__ walpha_b,
                          int* __restrict__ cur, int4* __restrict__ rec_obj,
                          int2* __restrict__ rec_sub, int E, int N) {
  int e = blockIdx.x * blockDim.x + threadIdx.x;
  if (e >= E) return;
  int ridx = edges[e * 6 + 0];
  int rel  = edges[e * 6 + 2];
  int sub  = edges[e * 6 + 4];
  int obj  = edges[e * 6 + 5];
  float z = walpha_b[0];
#pragma unroll
  for (int j = 0; j < 5; j++) {
    float vj = P[(size_t)sub * 5 + j] + s2[rel * 5 + j] + s3[ridx * 5 + j];
    z += fmaxf(vj, 0.f) * walpha_w[j];
  }
  float a = 1.f / (1.f + expf(-z));
  int p = atomicAdd(&cur[obj], 1);
  rec_obj[p] = make_int4(sub, rel, __float_as_int(a), 0);
  int q = atomicAdd(&cur[N + sub], 1) - E;
  rec_sub[q] = make_int2(obj, sub);
}

// ---------- K5: segment_max by obj (atomic-free, wave/NPW-nodes) -> agg (= d_out)
__global__ void k_agg(const int* __restrict__ off, const int4* __restrict__ rec_obj,
                      const float* __restrict__ hidden, const float* __restrict__ rela,
                      float* __restrict__ agg, int N) {
  int lane = threadIdx.x & 63;
  int wid  = blockIdx.x * (blockDim.x >> 6) + (threadIdx.x >> 6);
  int node0 = wid * NPW;
  if (node0 >= N) return;
  int ov = 0;
  if (lane <= NPW) {
    int idx = node0 + lane;
    if (idx > N) idx = N;
    ov = off[idx];
  }
  int B   = __shfl(ov, 0);
  int End = __shfl(ov, NPW);
  int lbase = B;
  int rx = 0, ry = 0; float rz = 0.f;
  {
    int p = lbase + lane;
    if (p < End) { int4 r = rec_obj[p]; rx = r.x; ry = r.y; rz = __int_as_float(r.z); }
  }
  int cur = B;
  for (int i = 0; i < NPW; i++) {
    int node = node0 + i;
    if (node >= N) break;
    int en = __shfl(ov, i + 1);
    int bst = cur;
    float vmax = -FLT_MAX;
    while (cur < en) {
      int idx = cur - lbase;
      if (idx >= 64) {           // wave-uniform reload of next 64 records
        lbase += 64;
        int p = lbase + lane;
        if (p < End) { int4 r = rec_obj[p]; rx = r.x; ry = r.y; rz = __int_as_float(r.z); }
        idx = 0;
      }
      int sub = __shfl(rx, idx);
      int rel = __shfl(ry, idx);
      float a = __int_as_float(__shfl(__float_as_int(rz), idx));
      float x = a * (hidden[(size_t)sub * 64 + lane] - rela[rel * 64 + lane]);
      vmax = fmaxf(vmax, x);
      cur++;
    }
    agg[(size_t)node * 64 + lane] = (en > bst) ? vmax : 0.f;
  }
}

// ---------- K6: h-split thread-per-node GEMM. blockIdx.y = h selects output
// half (cols h*32..h*32+31): acc[32]/thread (VGPR ~48 -> ~2x occupancy vs r5's
// acc[64]), weights W2[k*64+h*32+j] uniform per block -> s_load, 1 FMA/MAC.
// h=0 thread also computes u = a·fu; h=1 computes v = a·fv (full row streamed).
// Reads A = d_out (agg), writes B = ws.agg2 -> no in-place race.
__global__ void __launch_bounds__(128)
k_trans2(const float* __restrict__ A, const float* __restrict__ W2,
         const float* __restrict__ fuv, float* __restrict__ Bo,
         float* __restrict__ u, float* __restrict__ v, int N) {
  __shared__ float lds[128 * 32];  // 16 KB
  int tid = threadIdx.x;
  int h = blockIdx.y;
  int n0 = blockIdx.x * 128;
  int n = n0 + tid;
  if (n < N) {
    float acc[32];
#pragma unroll
    for (int j = 0; j < 32; j++) acc[j] = 0.f;
    float uvacc = 0.f;
    const float* fvec = fuv + h * 64;         // uniform -> s_load
    const float* Wb = W2 + h * 32;            // uniform base
    const float4* A4 = (const float4*)(A + (size_t)n * 64);
#pragma unroll
    for (int k4 = 0; k4 < 16; k4++) {
      float4 a4 = A4[k4];
      float av[4] = {a4.x, a4.y, a4.z, a4.w};
#pragma unroll
      for (int q = 0; q < 4; q++) {
        int k = k4 * 4 + q;
        float ak = av[q];
        uvacc += ak * fvec[k];                // uniform -> s_load
#pragma unroll
        for (int j = 0; j < 32; j++) acc[j] += ak * Wb[k * 64 + j];  // uniform -> s_load
      }
    }
    if (h == 0) u[n] = uvacc; else v[n] = uvacc;
    // stage half-row to LDS (XOR-swizzled float4 granules, r4-verified family)
#pragma unroll
    for (int j4 = 0; j4 < 8; j4++) {
      int pos = j4 ^ (tid & 7);
      *(float4*)&lds[tid * 32 + pos * 4] =
          make_float4(acc[j4 * 4], acc[j4 * 4 + 1], acc[j4 * 4 + 2], acc[j4 * 4 + 3]);
    }
  }
  __syncthreads();
  // coalesced copy-out: 128 rows x 8 float4 (half-rows, 128B contiguous segments)
#pragma unroll
  for (int i = 0; i < 8; i++) {
    int f = tid + 128 * i;
    int row = f >> 3, c4 = f & 7;
    if (n0 + row < N) {
      int pos = c4 ^ (row & 7);
      *(float4*)&Bo[(size_t)(n0 + row) * 64 + h * 32 + c4 * 4] =
          *(float4*)&lds[row * 32 + pos * 4];
    }
  }
}

// ---------- K7: scores in sub-CSR position order + softmax partials
__global__ void k_scores(const int2* __restrict__ rec_sub, const float* __restrict__ u,
                         const float* __restrict__ v, const float* __restrict__ fb,
                         float* __restrict__ scores, float* __restrict__ pmax,
                         float* __restrict__ psum, int E) {
  __shared__ float red_m[256], red_s[256];
  float b = fb[0];
  float lm = -FLT_MAX, ls = 0.f;
  for (int pos = blockIdx.x * blockDim.x + threadIdx.x; pos < E; pos += gridDim.x * blockDim.x) {
    int2 r = rec_sub[pos];
    float s = u[r.y] + v[r.x] + b;
    s = (s >= 0.f) ? s : 0.2f * s;
    scores[pos] = s;
    if (s > lm) { ls = ls * expf(lm - s) + 1.f; lm = s; }
    else        { ls += expf(s - lm); }
  }
  red_m[threadIdx.x] = lm; red_s[threadIdx.x] = ls;
  __syncthreads();
  for (int d = blockDim.x / 2; d > 0; d >>= 1) {
    if (threadIdx.x < d) {
      float m1 = red_m[threadIdx.x], s1 = red_s[threadIdx.x];
      float m2 = red_m[threadIdx.x + d], s2 = red_s[threadIdx.x + d];
      float m = fmaxf(m1, m2);
      float s = 0.f;
      if (m > -FLT_MAX) s = s1 * expf(m1 - m) + s2 * expf(m2 - m);
      red_m[threadIdx.x] = m; red_s[threadIdx.x] = s;
    }
    __syncthreads();
  }
  if (threadIdx.x == 0) { pmax[blockIdx.x] = red_m[0]; psum[blockIdx.x] = red_s[0]; }
}

// ---------- K8
__global__ void k_softmax_final(const float* __restrict__ pmax, const float* __restrict__ psum,
                                float* __restrict__ scal, int G) {
  __shared__ float red_m[256], red_s[256];
  float lm = -FLT_MAX, ls = 0.f;
  for (int i = threadIdx.x; i < G; i += 256) {
    float m2 = pmax[i], s2 = psum[i];
    if (m2 > lm) { ls = ls * expf(lm - m2) + s2; lm = m2; }
    else         { ls += s2 * expf(m2 - lm); }
  }
  red_m[threadIdx.x] = lm; red_s[threadIdx.x] = ls;
  __syncthreads();
  for (int d = 128; d > 0; d >>= 1) {
    if (threadIdx.x < d) {
      float m1 = red_m[threadIdx.x], s1 = red_s[threadIdx.x];
      float m2 = red_m[threadIdx.x + d], s2 = red_s[threadIdx.x + d];
      float m = fmaxf(m1, m2);
      float s = 0.f;
      if (m > -FLT_MAX) s = s1 * expf(m1 - m) + s2 * expf(m2 - m);
      red_m[threadIdx.x] = m; red_s[threadIdx.x] = s;
    }
    __syncthreads();
  }
  if (threadIdx.x == 0) { scal[0] = red_m[0]; scal[1] = red_s[0]; }
}

// ---------- K9: weighted segment_sum by sub (atomic-free, wave/NPW-nodes)
// exp(score-gmax) folded at record load (once per edge; replaces k_expw pass,
// identical values — r9-verified). Gathers ws.agg2, writes FINAL out -> d_out.
__global__ void k_aggsum(const int* __restrict__ off, const int2* __restrict__ rec_sub,
                         const float* __restrict__ scores, const float* __restrict__ agg2,
                         const float* __restrict__ bias, const float* __restrict__ scal,
                         float* __restrict__ out, int N, int E) {
  int lane = threadIdx.x & 63;
  int wid  = blockIdx.x * (blockDim.x >> 6) + (threadIdx.x >> 6);
  int node0 = wid * NPW;
  if (node0 >= N) return;
  float bl = bias[lane];
  float gmax = scal[0];
  float inv = 1.f / scal[1];
  int ov = 0;
  if (lane <= NPW) {
    int idx = node0 + lane;
    ov = (idx >= N) ? E : (off[N + idx] - E);
  }
  int B   = __shfl(ov, 0);
  int End = __shfl(ov, NPW);
  int lbase = B;
  int objr = 0; float wr = 0.f;
  {
    int p = lbase + lane;
    if (p < End) { objr = rec_sub[p].x; wr = expf(scores[p] - gmax); }
  }
  int cur = B;
  for (int i = 0; i < NPW; i++) {
    int node = node0 + i;
    if (node >= N) break;
    int en = __shfl(ov, i + 1);
    float acc = 0.f, wa = 0.f;
    while (cur < en) {
      int idx = cur - lbase;
      if (idx >= 64) {           // wave-uniform reload
        lbase += 64;
        int p = lbase + lane;
        if (p < End) { objr = rec_sub[p].x; wr = expf(scores[p] - gmax); }
        idx = 0;
      }
      int obj = __shfl(objr, idx);
      float ww = __int_as_float(__shfl(__float_as_int(wr), idx));
      acc += ww * agg2[(size_t)obj * 64 + lane];
      wa  += ww;
      cur++;
    }
    out[(size_t)node * 64 + lane] = (acc + wa * bl) * inv;
  }
}

extern "C" void kernel_launch(void* const* d_in, const int* in_sizes, int n_in,
                              void* d_out, int out_size, void* d_ws, size_t ws_size,
                              hipStream_t stream) {
  const float* hidden    = (const float*)d_in[0];
  const float* rela      = (const float*)d_in[1];
  const float* Ws        = (const float*)d_in[2];
  const float* Wr        = (const float*)d_in[3];
  const float* Wqr_w     = (const float*)d_in[4];
  const float* Wqr_b     = (const float*)d_in[5];
  const float* walpha_w  = (const float*)d_in[6];
  const float* walpha_b  = (const float*)d_in[7];
  const float* Wh        = (const float*)d_in[8];
  const float* attn_fc_w = (const float*)d_in[9];
  const float* attn_fc_b = (const float*)d_in[10];
  const float* Wnode_w   = (const float*)d_in[11];
  const float* Wnode_b   = (const float*)d_in[12];
  const int*   q_rel     = (const int*)d_in[14];
  const int*   edges     = (const int*)d_in[15];

  int N = in_sizes[0] / 64;      // 500000
  int E = in_sizes[15] / 6;      // 1000000
  int nrel = in_sizes[1] / 64;   // 401
  int batch = in_sizes[14];      // 32

  // workspace layout: every buffer 256 B aligned
  char* w = (char*)d_ws;
  size_t o = 0;
  #define WS_ALLOC(ptr_t, name, bytes) \
    ptr_t name = (ptr_t)(w + o); o = (o + (size_t)(bytes) + 255) & ~(size_t)255;
  WS_ALLOC(float*, agg2,    (size_t)N * 64 * 4)    // agg2 = agg@W2 (agg lives in d_out)
  WS_ALLOC(float*, P,       (size_t)N * 5 * 4)     // later: u,v alias here
  WS_ALLOC(int4*,  rec_obj, (size_t)E * 16)
  WS_ALLOC(int2*,  rec_sub, (size_t)E * 8)
  WS_ALLOC(int*,   cnt,     (size_t)2 * N * 4)     // counts -> cursors; later scores alias
  WS_ALLOC(int*,   off,     (size_t)2 * N * 4)
  WS_ALLOC(int*,   part,    1024 * 4)
  WS_ALLOC(float*, pmax,    SOFT_G * 4)
  WS_ALLOC(float*, psum,    SOFT_G * 4)
  WS_ALLOC(float*, s2t,     (size_t)nrel * 5 * 4)
  WS_ALLOC(float*, s3t,     (size_t)batch * 5 * 4)
  WS_ALLOC(float*, scal,    2 * 4)
  WS_ALLOC(float*, W2,      64 * 64 * 4)
  WS_ALLOC(float*, fuv,     2 * 64 * 4)
  #undef WS_ALLOC

  float* u = P;                 // P dead after k_scatter
  float* v = P + N;
  float* scores = (float*)cnt;  // cursors dead after k_scatter (E*4 <= 2N*4)
  float* aggbuf = (float*)d_out; // agg rows live in d_out until k_aggsum overwrites

  k_prep<<<256, 256, 0, stream>>>(rela, Wr, Wqr_w, Wqr_b, q_rel, Wh, Wnode_w, attn_fc_w,
                                  s2t, s3t, W2, fuv, cnt, nrel, batch, 2 * N);
  k_proj_hist<<<(E + 255) / 256, 256, 0, stream>>>(hidden, Ws, edges, P, cnt, N, E);
  int SCAN_N = 2 * N;
  int nblk = (SCAN_N + SCAN_CHUNK - 1) / SCAN_CHUNK;  // 977 <= 1024
  k_scan_partial<<<nblk, SCAN_BLK, 0, stream>>>(cnt, part, SCAN_N);
  k_scan_top<<<1, 1024, 0, stream>>>(part, nblk);
  k_scan_final<<<nblk, SCAN_BLK, 0, stream>>>(cnt, part, off, SCAN_N);  // off + cursors
  k_scatter<<<(E + 255) / 256, 256, 0, stream>>>(edges, P, s2t, s3t, walpha_w, walpha_b,
                                                 cnt, rec_obj, rec_sub, E, N);
  // batched CSR kernels: NPW nodes per wave, 4 waves per block
  int csr_blocks = (N + NPW * 4 - 1) / (NPW * 4);
  k_agg<<<csr_blocks, 256, 0, stream>>>(off, rec_obj, hidden, rela, aggbuf, N);
  dim3 tgrid((N + 127) / 128, 2);
  k_trans2<<<tgrid, 128, 0, stream>>>(aggbuf, W2, fuv, agg2, u, v, N);
  k_scores<<<SOFT_G, 256, 0, stream>>>(rec_sub, u, v, attn_fc_b, scores, pmax, psum, E);
  k_softmax_final<<<1, 256, 0, stream>>>(pmax, psum, scal, SOFT_G);
  k_aggsum<<<csr_blocks, 256, 0, stream>>>(off, rec_sub, scores, agg2,
                                           Wnode_b, scal, (float*)d_out, N, E);
}